// Round 2
// baseline (8185.890 us; speedup 1.0000x reference)
//
#include <hip/hip_runtime.h>

#define SD 2048      // state dim
#define OD 512       // obs dim
#define NT 8192      // steps
#define KB 128       // blocks of 64 steps
#define PROC_STD 0.31622776601683794f
#define OBS_STD  0.7071067811865476f

typedef __attribute__((ext_vector_type(8))) short v8s;
typedef __attribute__((ext_vector_type(4))) float v4f;

__device__ __forceinline__ unsigned short f2bf(float f) {
    union { float f; unsigned u; } v; v.f = f;
    unsigned r = v.u + 0x7fffu + ((v.u >> 16) & 1u);
    return (unsigned short)(r >> 16);
}
__device__ __forceinline__ float b2f(unsigned short u) {
    union { unsigned u; float f; } v; v.u = ((unsigned)u) << 16;
    return v.f;
}

// ---------- frag-layout prep: store element (row,col) at [(col/8)*ROWS*8 + row*8 + col%8]
// (A-operand layout: 16 consecutive rows x 16B = 256B coalesced frag loads)
__global__ __launch_bounds__(256) void k_prep_E(const float* __restrict__ A,
                                                unsigned short* __restrict__ Efr,
                                                unsigned short* __restrict__ Etfr) {
    int idx = blockIdx.x * 256 + threadIdx.x;
    int r = idx >> 11, c = idx & 2047;
    float e = A[idx] - (r == c ? 0.99f : 0.f);
    unsigned short b = f2bf(e);
    Efr [((size_t)(c >> 3)) * 16384 + r * 8 + (c & 7)] = b;  // A-layout (k=c)
    Etfr[((size_t)(r >> 3)) * 16384 + c * 8 + (r & 7)] = b;  // B-layout (k=r)
}

__global__ __launch_bounds__(256) void k_prep_C(const float* __restrict__ C,
                                                unsigned short* __restrict__ Cfr) {
    int idx = blockIdx.x * 256 + threadIdx.x;
    int o = idx >> 11, c = idx & 2047;
    Cfr[((size_t)(c >> 3)) * 4096 + o * 8 + (c & 7)] = f2bf(C[idx]);
}

// ---------- power GEMM: O = A(2048x2048) @ B(2048x2048), all frag-layout, out in B-layout
__global__ __launch_bounds__(256) void k_gemm_fr(const unsigned short* __restrict__ Afr,
                                                 const unsigned short* __restrict__ Bfr,
                                                 unsigned short* __restrict__ Ofr) {
    int bx = blockIdx.x;
    int mt = (bx & 31) * 64, nt = (bx >> 5) * 64;
    int tid = threadIdx.x, lane = tid & 63, w = tid >> 6;
    int m16 = lane & 15, g = lane >> 4;
    int wm = (w & 1) * 32, wn = (w >> 1) * 32;
    v4f acc[2][2] = {{{0,0,0,0},{0,0,0,0}},{{0,0,0,0},{0,0,0,0}}};
    const unsigned short* Ap = Afr + (size_t)g * 16384 + (mt + wm + m16) * 8;
    const unsigned short* Bp = Bfr + (size_t)g * 16384 + (nt + wn + m16) * 8;
#pragma unroll 4
    for (int kk = 0; kk < 64; ++kk) {
        size_t off = (size_t)kk * 65536;
        v8s a0 = *(const v8s*)(Ap + off);
        v8s a1 = *(const v8s*)(Ap + off + 128);
        v8s b0 = *(const v8s*)(Bp + off);
        v8s b1 = *(const v8s*)(Bp + off + 128);
        acc[0][0] = __builtin_amdgcn_mfma_f32_16x16x32_bf16(a0, b0, acc[0][0], 0, 0, 0);
        acc[1][0] = __builtin_amdgcn_mfma_f32_16x16x32_bf16(a1, b0, acc[1][0], 0, 0, 0);
        acc[0][1] = __builtin_amdgcn_mfma_f32_16x16x32_bf16(a0, b1, acc[0][1], 0, 0, 0);
        acc[1][1] = __builtin_amdgcn_mfma_f32_16x16x32_bf16(a1, b1, acc[1][1], 0, 0, 0);
    }
#pragma unroll
    for (int mi = 0; mi < 2; ++mi)
#pragma unroll
        for (int ni = 0; ni < 2; ++ni) {
            int mb = mt + wm + mi * 16 + g * 4;           // row base (4 consecutive)
            int n  = nt + wn + ni * 16 + m16;             // col
            short4 pk;
            pk.x = (short)f2bf(acc[mi][ni][0]);
            pk.y = (short)f2bf(acc[mi][ni][1]);
            pk.z = (short)f2bf(acc[mi][ni][2]);
            pk.w = (short)f2bf(acc[mi][ni][3]);
            *(short4*)(Ofr + ((size_t)(mb >> 3)) * 16384 + n * 8 + (mb & 7)) = pk;
        }
}

// ---------- Mbf = bf16( c1*E + c2*E^2 + c3*E^3 + c4*E^4 )  (A^64 = a64*I + M)
__global__ __launch_bounds__(256) void k_combine(const float* __restrict__ A,
                                                 const unsigned short* __restrict__ E2,
                                                 const unsigned short* __restrict__ E3,
                                                 const unsigned short* __restrict__ E4,
                                                 unsigned short* __restrict__ Mbf,
                                                 float c1, float c2, float c3, float c4) {
    int idx = blockIdx.x * 256 + threadIdx.x;
    int r = idx >> 11, c = idx & 2047;
    size_t fo = ((size_t)(r >> 3)) * 16384 + c * 8 + (r & 7);
    float m = c1 * (A[idx] - (r == c ? 0.99f : 0.f))
            + c2 * b2f(E2[fo]) + c3 * b2f(E3[fo]) + c4 * b2f(E4[fo]);
    Mbf[idx] = f2bf(m);
}

// ---------- device-scope grid barrier (grid=256, all co-resident: 256 thr, no LDS)
__device__ __forceinline__ void gbar(unsigned* flags, unsigned* genp,
                                     int bx, int tid, unsigned g) {
    __syncthreads();
    if (bx == 0) {
        if (tid > 0) {
            while (__hip_atomic_load(flags + tid * 4, __ATOMIC_ACQUIRE,
                                     __HIP_MEMORY_SCOPE_AGENT) < g)
                __builtin_amdgcn_s_sleep(2);
        }
        __syncthreads();
        if (tid == 0)
            __hip_atomic_store(genp, g, __ATOMIC_RELEASE, __HIP_MEMORY_SCOPE_AGENT);
    } else {
        if (tid == 0) {
            __hip_atomic_store(flags + bx * 4, g, __ATOMIC_RELEASE,
                               __HIP_MEMORY_SCOPE_AGENT);
            while (__hip_atomic_load(genp, __ATOMIC_ACQUIRE,
                                     __HIP_MEMORY_SCOPE_AGENT) < g)
                __builtin_amdgcn_s_sleep(2);
        }
        __syncthreads();
    }
}

// ---------- one scan step: X_out = 0.99*X_in + E@X_in + PROC_STD*pn[t]   (batch 128)
__device__ __forceinline__ void step_body(const unsigned short* __restrict__ Efr,
                                          const unsigned short* __restrict__ Xfr_in,
                                          const float* __restrict__ X32in,
                                          float* __restrict__ X32out,
                                          unsigned short* __restrict__ Xfr_out,
                                          unsigned short* __restrict__ Sfr,
                                          const float* __restrict__ pn,
                                          int i, int pass3, int bx, int tid) {
    int lane = tid & 63, w = tid >> 6;
    int m16 = lane & 15, g = lane >> 4;
    int mt = bx >> 2, nt = bx & 3;
    int drow = mt * 32 + (w >> 1) * 16 + m16;     // A row
    int kb   = nt * 32 + (w & 1) * 16 + m16;      // B col (block id)
    v4f acc = {0, 0, 0, 0};
    const unsigned short* Ap = Efr + (size_t)g * 16384 + drow * 8;
    const unsigned short* Bp = Xfr_in + (size_t)g * 1024 + kb * 8;
#pragma unroll 8
    for (int kk = 0; kk < 64; ++kk) {
        v8s a = *(const v8s*)(Ap + (size_t)kk * 65536);
        v8s b = *(const v8s*)(Bp + (size_t)kk * 4096);
        acc = __builtin_amdgcn_mfma_f32_16x16x32_bf16(a, b, acc, 0, 0, 0);
    }
    int dbase = mt * 32 + (w >> 1) * 16 + g * 4;
    int tn = kb * 64 + i - pass3;                 // noise time index
    size_t i32 = (size_t)kb * SD + dbase;
    float4 xin = *(const float4*)(X32in + i32);
    float4 pn4 = *(const float4*)(pn + (size_t)tn * SD + dbase);
    float4 vo;
    vo.x = 0.99f * xin.x + acc[0] + PROC_STD * pn4.x;
    vo.y = 0.99f * xin.y + acc[1] + PROC_STD * pn4.y;
    vo.z = 0.99f * xin.z + acc[2] + PROC_STD * pn4.z;
    vo.w = 0.99f * xin.w + acc[3] + PROC_STD * pn4.w;
    *(float4*)(X32out + i32) = vo;
    short4 pk;
    pk.x = (short)f2bf(vo.x); pk.y = (short)f2bf(vo.y);
    pk.z = (short)f2bf(vo.z); pk.w = (short)f2bf(vo.w);
    *(short4*)(Xfr_out + ((size_t)(dbase >> 3)) * 1024 + kb * 8 + (dbase & 7)) = pk;
    if (pass3)
        *(short4*)(Sfr + ((size_t)(dbase >> 3)) * 65536 +
                   (size_t)(kb * 64 + i) * 8 + (dbase & 7)) = pk;
}

// ---------- boundary matvec: s_out = a64*s_in + Mbf@s_in + Ufin_k
__device__ __forceinline__ void mv_body(const unsigned short* __restrict__ Mbf,
                                        const float* __restrict__ sin_,
                                        const float* __restrict__ Ufin_k,
                                        float* __restrict__ sout,
                                        float a64, int bx, int tid) {
    int lane = tid & 63, w = tid >> 6;
    int r0 = bx * 8 + w * 2;
#pragma unroll
    for (int rr = 0; rr < 2; ++rr) {
        int r = r0 + rr;
        const unsigned short* Mr = Mbf + (size_t)r * SD;
        float accu = 0.f;
#pragma unroll
        for (int it = 0; it < 4; ++it) {
            int c = lane * 8 + it * 512;
            v8s m8 = *(const v8s*)(Mr + c);
            float4 sa = *(const float4*)(sin_ + c);
            float4 sb = *(const float4*)(sin_ + c + 4);
            accu += b2f((unsigned short)m8[0]) * sa.x + b2f((unsigned short)m8[1]) * sa.y
                  + b2f((unsigned short)m8[2]) * sa.z + b2f((unsigned short)m8[3]) * sa.w
                  + b2f((unsigned short)m8[4]) * sb.x + b2f((unsigned short)m8[5]) * sb.y
                  + b2f((unsigned short)m8[6]) * sb.z + b2f((unsigned short)m8[7]) * sb.w;
        }
#pragma unroll
        for (int off = 32; off; off >>= 1) accu += __shfl_down(accu, off);
        if (lane == 0) sout[r] = a64 * sin_[r] + accu + Ufin_k[r];
    }
}

// ---------- persistent scan kernel: pass1 + pass2 + pass3 with grid barriers
__global__ __launch_bounds__(256) void k_coop(const unsigned short* __restrict__ Efr,
                                              const unsigned short* __restrict__ Mbf,
                                              const float* __restrict__ s0,
                                              const float* __restrict__ pn,
                                              float* __restrict__ U32a,
                                              float* __restrict__ U32b,
                                              unsigned short* __restrict__ Ufra,
                                              unsigned short* __restrict__ Ufrb,
                                              float* __restrict__ Sb,
                                              unsigned short* __restrict__ Sfr,
                                              unsigned* flags, unsigned* genp,
                                              float a64) {
    int bx = blockIdx.x, tid = threadIdx.x;
    int gtid = bx * 256 + tid;
    float* U32[2] = {U32a, U32b};
    unsigned short* Ufr[2] = {Ufra, Ufrb};
    unsigned gseq = 0;

    // init pass1: u = PROC_STD * pn[k*64]   (layout [kb][d] fp32 + frag bf16)
    for (int idx = gtid; idx < SD * KB; idx += 65536) {
        int kb = idx >> 11, d = idx & 2047;
        float v = PROC_STD * pn[(size_t)(kb * 64) * SD + d];
        U32a[idx] = v;
        Ufra[((size_t)(d >> 3)) * 1024 + kb * 8 + (d & 7)] = f2bf(v);
    }
    if (gtid < SD) Sb[gtid] = s0[gtid];
    gbar(flags, genp, bx, tid, ++gseq);

    // pass1: 63 batched noise-accumulation steps
    for (int i = 1; i <= 63; ++i) {
        step_body(Efr, Ufr[(i - 1) & 1], U32[(i - 1) & 1], U32[i & 1], Ufr[i & 1],
                  (unsigned short*)0, pn, i, 0, bx, tid);
        gbar(flags, genp, bx, tid, ++gseq);
    }
    // pass2: 127 sequential boundary matvecs (Ufin = U32[1] after 63 steps)
    for (int k = 0; k < KB - 1; ++k) {
        mv_body(Mbf, Sb + (size_t)k * SD, U32b + (size_t)k * SD,
                Sb + (size_t)(k + 1) * SD, a64, bx, tid);
        gbar(flags, genp, bx, tid, ++gseq);
    }
    // init pass3 from boundary states; also emit S at t = kb*64
    for (int idx = gtid; idx < SD * KB; idx += 65536) {
        int kb = idx >> 11, d = idx & 2047;
        float v = Sb[idx];
        U32a[idx] = v;
        unsigned short bv = f2bf(v);
        Ufra[((size_t)(d >> 3)) * 1024 + kb * 8 + (d & 7)] = bv;
        Sfr[((size_t)(d >> 3)) * 65536 + (size_t)(kb * 64) * 8 + (d & 7)] = bv;
    }
    gbar(flags, genp, bx, tid, ++gseq);

    // pass3: 63 replay steps, streaming bf16 states into Sfr
    for (int i = 1; i <= 63; ++i) {
        step_body(Efr, Ufr[(i - 1) & 1], U32[(i - 1) & 1], U32[i & 1], Ufr[i & 1],
                  Sfr, pn, i, 1, bx, tid);
        gbar(flags, genp, bx, tid, ++gseq);
    }
}

// ---------- final obs GEMM: out[t][o] = Cfr @ Sfr + OBS_STD * on
__global__ __launch_bounds__(256) void k_obs(const unsigned short* __restrict__ Cfr,
                                             const unsigned short* __restrict__ Sfr,
                                             const float* __restrict__ on,
                                             float* __restrict__ out) {
    int bx = blockIdx.x;
    int ot = (bx & 7) * 64, tt = (bx >> 3) * 64;
    int tid = threadIdx.x, lane = tid & 63, w = tid >> 6;
    int m16 = lane & 15, g = lane >> 4;
    int wo = (w & 1) * 32, wt = (w >> 1) * 32;
    v4f acc[2][2] = {{{0,0,0,0},{0,0,0,0}},{{0,0,0,0},{0,0,0,0}}};
    const unsigned short* Ap = Cfr + (size_t)g * 4096 + (ot + wo + m16) * 8;
    const unsigned short* Bp = Sfr + (size_t)g * 65536 + (tt + wt + m16) * 8;
#pragma unroll 4
    for (int kk = 0; kk < 64; ++kk) {
        v8s a0 = *(const v8s*)(Ap + (size_t)kk * 16384);
        v8s a1 = *(const v8s*)(Ap + (size_t)kk * 16384 + 128);
        v8s b0 = *(const v8s*)(Bp + (size_t)kk * 262144);
        v8s b1 = *(const v8s*)(Bp + (size_t)kk * 262144 + 128);
        acc[0][0] = __builtin_amdgcn_mfma_f32_16x16x32_bf16(a0, b0, acc[0][0], 0, 0, 0);
        acc[1][0] = __builtin_amdgcn_mfma_f32_16x16x32_bf16(a1, b0, acc[1][0], 0, 0, 0);
        acc[0][1] = __builtin_amdgcn_mfma_f32_16x16x32_bf16(a0, b1, acc[0][1], 0, 0, 0);
        acc[1][1] = __builtin_amdgcn_mfma_f32_16x16x32_bf16(a1, b1, acc[1][1], 0, 0, 0);
    }
#pragma unroll
    for (int mi = 0; mi < 2; ++mi)
#pragma unroll
        for (int ni = 0; ni < 2; ++ni) {
            int o = ot + wo + mi * 16 + g * 4;
            int t = tt + wt + ni * 16 + m16;
            size_t base = (size_t)t * OD + o;
            float4 n4 = *(const float4*)(on + base);
            float4 o4;
            o4.x = acc[mi][ni][0] + OBS_STD * n4.x;
            o4.y = acc[mi][ni][1] + OBS_STD * n4.y;
            o4.z = acc[mi][ni][2] + OBS_STD * n4.z;
            o4.w = acc[mi][ni][3] + OBS_STD * n4.w;
            *(float4*)(out + base) = o4;
        }
}

// ---------- host ----------
extern "C" void kernel_launch(void* const* d_in, const int* in_sizes, int n_in,
                              void* d_out, int out_size, void* d_ws, size_t ws_size,
                              hipStream_t stream) {
    const float* s0 = (const float*)d_in[0];
    const float* A  = (const float*)d_in[1];
    const float* C  = (const float*)d_in[2];
    const float* pn = (const float*)d_in[3];
    const float* on = (const float*)d_in[4];
    float* out = (float*)d_out;

    char* p = (char*)d_ws;
    auto take = [&](size_t n) { char* r = p; p += (n + 255) & ~(size_t)255; return r; };
    unsigned* bar = (unsigned*)take(8192);                               // flags + gen
    unsigned short* Efr = (unsigned short*)take((size_t)SD * SD * 2);    // 8 MB
    unsigned short* Cfr = (unsigned short*)take((size_t)OD * SD * 2);    // 2 MB
    float* U32a = (float*)take((size_t)SD * KB * 4);
    float* U32b = (float*)take((size_t)SD * KB * 4);
    unsigned short* Ufra = (unsigned short*)take((size_t)SD * KB * 2);
    unsigned short* Ufrb = (unsigned short*)take((size_t)SD * KB * 2);
    float* Sb = (float*)take((size_t)KB * SD * 4);                       // boundary states
    char* R = take((size_t)SD * NT * 2);                                 // 32 MB region
    unsigned short* Sfr  = (unsigned short*)R;            // coop/obs phase
    unsigned short* Etfr = (unsigned short*)R;            // prep phase (dead before Sfr)
    unsigned short* E3   = (unsigned short*)(R + (size_t)SD * SD * 2);
    unsigned short* E4   = (unsigned short*)(R + (size_t)SD * SD * 4);
    // d_out (16 MB) doubles as scratch until k_obs overwrites it:
    unsigned short* Mbf = (unsigned short*)d_out;                        // 8 MB
    unsigned short* E2  = (unsigned short*)((char*)d_out + (size_t)SD * SD * 2);

    // A^64 = 0.99^64 I + sum_{m=1..4} C(64,m) 0.99^(64-m) E^m  (tail ~2e-3 spectral, ok)
    double p99[65]; p99[0] = 1.0;
    for (int m = 1; m <= 64; ++m) p99[m] = p99[m - 1] * 0.99;
    float cf1 = (float)(64.0 * p99[63]);
    float cf2 = (float)(2016.0 * p99[62]);
    float cf3 = (float)(41664.0 * p99[61]);
    float cf4 = (float)(635376.0 * p99[60]);
    float a64 = (float)p99[64];

    hipMemsetAsync(bar, 0, 8192, stream);
    k_prep_E<<<SD * SD / 256, 256, 0, stream>>>(A, Efr, Etfr);
    k_prep_C<<<OD * SD / 256, 256, 0, stream>>>(C, Cfr);
    k_gemm_fr<<<1024, 256, 0, stream>>>(Efr, Etfr, E2);   // E^2
    k_gemm_fr<<<1024, 256, 0, stream>>>(Efr, E2, E3);     // E^3
    k_gemm_fr<<<1024, 256, 0, stream>>>(Efr, E3, E4);     // E^4
    k_combine<<<SD * SD / 256, 256, 0, stream>>>(A, E2, E3, E4, Mbf, cf1, cf2, cf3, cf4);
    k_coop<<<256, 256, 0, stream>>>(Efr, Mbf, s0, pn, U32a, U32b, Ufra, Ufrb,
                                    Sb, Sfr, bar, bar + 1024, a64);
    k_obs<<<1024, 256, 0, stream>>>(Cfr, Sfr, on, out);
}

// Round 3
// 3595.819 us; speedup vs baseline: 2.2765x; 2.2765x over previous
//
#include <hip/hip_runtime.h>

#define SD 2048      // state dim
#define OD 512       // obs dim
#define NT 8192      // steps
#define KB 128       // blocks of 64 steps
#define PROC_STD 0.31622776601683794f
#define OBS_STD  0.7071067811865476f
#define FSTRIDE 32   // flag spacing (128 B) to avoid L3-line contention

typedef __attribute__((ext_vector_type(8))) short v8s;
typedef __attribute__((ext_vector_type(4))) float v4f;

__device__ __forceinline__ unsigned short f2bf(float f) {
    union { float f; unsigned u; } v; v.f = f;
    unsigned r = v.u + 0x7fffu + ((v.u >> 16) & 1u);
    return (unsigned short)(r >> 16);
}
__device__ __forceinline__ float b2f(unsigned short u) {
    union { unsigned u; float f; } v; v.u = ((unsigned)u) << 16;
    return v.f;
}

// ---------- frag-layout prep: element (row,col) at [(col/8)*ROWS*8 + row*8 + col%8]
__global__ __launch_bounds__(256) void k_prep_E(const float* __restrict__ A,
                                                unsigned short* __restrict__ Efr,
                                                unsigned short* __restrict__ Etfr) {
    int idx = blockIdx.x * 256 + threadIdx.x;
    int r = idx >> 11, c = idx & 2047;
    float e = A[idx] - (r == c ? 0.99f : 0.f);
    unsigned short b = f2bf(e);
    Efr [((size_t)(c >> 3)) * 16384 + r * 8 + (c & 7)] = b;  // A-layout (k=c)
    Etfr[((size_t)(r >> 3)) * 16384 + c * 8 + (r & 7)] = b;  // B-layout (k=r)
}

__global__ __launch_bounds__(256) void k_prep_C(const float* __restrict__ C,
                                                unsigned short* __restrict__ Cfr) {
    int idx = blockIdx.x * 256 + threadIdx.x;
    int o = idx >> 11, c = idx & 2047;
    Cfr[((size_t)(c >> 3)) * 4096 + o * 8 + (c & 7)] = f2bf(C[idx]);
}

// ---------- power GEMM: O = A @ B (2048^3), frag-layout, output in B-layout
__global__ __launch_bounds__(256) void k_gemm_fr(const unsigned short* __restrict__ Afr,
                                                 const unsigned short* __restrict__ Bfr,
                                                 unsigned short* __restrict__ Ofr) {
    int bx = blockIdx.x;
    int mt = (bx & 31) * 64, nt = (bx >> 5) * 64;
    int tid = threadIdx.x, lane = tid & 63, w = tid >> 6;
    int m16 = lane & 15, g = lane >> 4;
    int wm = (w & 1) * 32, wn = (w >> 1) * 32;
    v4f acc[2][2] = {{{0,0,0,0},{0,0,0,0}},{{0,0,0,0},{0,0,0,0}}};
    const unsigned short* Ap = Afr + (size_t)g * 16384 + (mt + wm + m16) * 8;
    const unsigned short* Bp = Bfr + (size_t)g * 16384 + (nt + wn + m16) * 8;
#pragma unroll 4
    for (int kk = 0; kk < 64; ++kk) {
        size_t off = (size_t)kk * 65536;
        v8s a0 = *(const v8s*)(Ap + off);
        v8s a1 = *(const v8s*)(Ap + off + 128);
        v8s b0 = *(const v8s*)(Bp + off);
        v8s b1 = *(const v8s*)(Bp + off + 128);
        acc[0][0] = __builtin_amdgcn_mfma_f32_16x16x32_bf16(a0, b0, acc[0][0], 0, 0, 0);
        acc[1][0] = __builtin_amdgcn_mfma_f32_16x16x32_bf16(a1, b0, acc[1][0], 0, 0, 0);
        acc[0][1] = __builtin_amdgcn_mfma_f32_16x16x32_bf16(a0, b1, acc[0][1], 0, 0, 0);
        acc[1][1] = __builtin_amdgcn_mfma_f32_16x16x32_bf16(a1, b1, acc[1][1], 0, 0, 0);
    }
#pragma unroll
    for (int mi = 0; mi < 2; ++mi)
#pragma unroll
        for (int ni = 0; ni < 2; ++ni) {
            int mb = mt + wm + mi * 16 + g * 4;
            int n  = nt + wn + ni * 16 + m16;
            short4 pk;
            pk.x = (short)f2bf(acc[mi][ni][0]);
            pk.y = (short)f2bf(acc[mi][ni][1]);
            pk.z = (short)f2bf(acc[mi][ni][2]);
            pk.w = (short)f2bf(acc[mi][ni][3]);
            *(short4*)(Ofr + ((size_t)(mb >> 3)) * 16384 + n * 8 + (mb & 7)) = pk;
        }
}

// ---------- Mbf = bf16( c1*E + c2*E^2 + c3*E^3 + c4*E^4 )  (A^64 = a64*I + M)
__global__ __launch_bounds__(256) void k_combine(const float* __restrict__ A,
                                                 const unsigned short* __restrict__ E2,
                                                 const unsigned short* __restrict__ E3,
                                                 const unsigned short* __restrict__ E4,
                                                 unsigned short* __restrict__ Mbf,
                                                 float c1, float c2, float c3, float c4) {
    int idx = blockIdx.x * 256 + threadIdx.x;
    int r = idx >> 11, c = idx & 2047;
    size_t fo = ((size_t)(r >> 3)) * 16384 + c * 8 + (r & 7);
    float m = c1 * (A[idx] - (r == c ? 0.99f : 0.f))
            + c2 * b2f(E2[fo]) + c3 * b2f(E3[fo]) + c4 * b2f(E4[fo]);
    Mbf[idx] = f2bf(m);
}

// ---------- grid barriers (grid=256, all co-resident). Relaxed polls only. ----------
// Fenced variant: one __threadfence() pair per block (release data / acquire data).
__device__ __forceinline__ void gbar_f(unsigned* flags, unsigned* genp,
                                       int bx, int tid, unsigned g) {
    __syncthreads();                       // drains each wave's vmem (stores in L2)
    if (bx == 0) {
        if (tid == 0) __threadfence();     // release block0's data (wbl2)
        __syncthreads();
        if (tid > 0) {
            while (__hip_atomic_load(flags + tid * FSTRIDE, __ATOMIC_RELAXED,
                                     __HIP_MEMORY_SCOPE_AGENT) < g)
                __builtin_amdgcn_s_sleep(2);
        }
        __syncthreads();
        if (tid == 0) {
            __threadfence();               // acquire gathered data (inv)
            __hip_atomic_store(genp, g, __ATOMIC_RELAXED, __HIP_MEMORY_SCOPE_AGENT);
        }
        __syncthreads();
    } else {
        if (tid == 0) {
            __threadfence();               // release this block's data (wbl2)
            __hip_atomic_store(flags + bx * FSTRIDE, g, __ATOMIC_RELAXED,
                               __HIP_MEMORY_SCOPE_AGENT);
            while (__hip_atomic_load(genp, __ATOMIC_RELAXED,
                                     __HIP_MEMORY_SCOPE_AGENT) < g)
                __builtin_amdgcn_s_sleep(2);
            __threadfence();               // acquire (inv)
        }
        __syncthreads();
    }
}

// Fence-free variant (pass2: all shared data moves via L2-bypassing atomics).
__device__ __forceinline__ void gbar_nf(unsigned* flags, unsigned* genp,
                                        int bx, int tid, unsigned g) {
    __syncthreads();
    if (bx == 0) {
        if (tid > 0) {
            while (__hip_atomic_load(flags + tid * FSTRIDE, __ATOMIC_RELAXED,
                                     __HIP_MEMORY_SCOPE_AGENT) < g)
                __builtin_amdgcn_s_sleep(2);
        }
        __syncthreads();
        if (tid == 0)
            __hip_atomic_store(genp, g, __ATOMIC_RELAXED, __HIP_MEMORY_SCOPE_AGENT);
        __syncthreads();
    } else {
        if (tid == 0) {
            __hip_atomic_store(flags + bx * FSTRIDE, g, __ATOMIC_RELAXED,
                               __HIP_MEMORY_SCOPE_AGENT);
            while (__hip_atomic_load(genp, __ATOMIC_RELAXED,
                                     __HIP_MEMORY_SCOPE_AGENT) < g)
                __builtin_amdgcn_s_sleep(2);
        }
        __syncthreads();
    }
}

// ---------- one scan step: X_out = 0.99*X_in + E@X_in + PROC_STD*pn[t]  (batch 128)
// XCD-swizzled tiles: xcd = bx&7 gets 8 consecutive mt groups (1 MB of E per XCD-L2)
__device__ __forceinline__ void step_body(const unsigned short* __restrict__ Efr,
                                          const unsigned short* __restrict__ Xfr_in,
                                          const float* __restrict__ X32in,
                                          float* __restrict__ X32out,
                                          unsigned short* __restrict__ Xfr_out,
                                          unsigned short* __restrict__ Sfr,
                                          const float* __restrict__ pn,
                                          int i, int pass3, int bx, int tid) {
    int lane = tid & 63, w = tid >> 6;
    int m16 = lane & 15, g = lane >> 4;
    int mt = (bx & 7) * 8 + (bx >> 5);            // XCD-local mt octet
    int nt = (bx >> 3) & 3;
    int drow = mt * 32 + (w >> 1) * 16 + m16;     // A row
    int kb   = nt * 32 + (w & 1) * 16 + m16;      // B col (block id)
    v4f acc = {0, 0, 0, 0};
    const unsigned short* Ap = Efr + (size_t)g * 16384 + drow * 8;
    const unsigned short* Bp = Xfr_in + (size_t)g * 1024 + kb * 8;
#pragma unroll 8
    for (int kk = 0; kk < 64; ++kk) {
        v8s a = *(const v8s*)(Ap + (size_t)kk * 65536);
        v8s b = *(const v8s*)(Bp + (size_t)kk * 4096);
        acc = __builtin_amdgcn_mfma_f32_16x16x32_bf16(a, b, acc, 0, 0, 0);
    }
    int dbase = mt * 32 + (w >> 1) * 16 + g * 4;
    int tn = kb * 64 + i - pass3;                 // noise time index
    size_t i32 = (size_t)kb * SD + dbase;
    float4 xin = *(const float4*)(X32in + i32);
    float4 pn4 = *(const float4*)(pn + (size_t)tn * SD + dbase);
    float4 vo;
    vo.x = 0.99f * xin.x + acc[0] + PROC_STD * pn4.x;
    vo.y = 0.99f * xin.y + acc[1] + PROC_STD * pn4.y;
    vo.z = 0.99f * xin.z + acc[2] + PROC_STD * pn4.z;
    vo.w = 0.99f * xin.w + acc[3] + PROC_STD * pn4.w;
    *(float4*)(X32out + i32) = vo;
    short4 pk;
    pk.x = (short)f2bf(vo.x); pk.y = (short)f2bf(vo.y);
    pk.z = (short)f2bf(vo.z); pk.w = (short)f2bf(vo.w);
    *(short4*)(Xfr_out + ((size_t)(dbase >> 3)) * 1024 + kb * 8 + (dbase & 7)) = pk;
    if (pass3)
        *(short4*)(Sfr + ((size_t)(dbase >> 3)) * 65536 +
                   (size_t)(kb * 64 + i) * 8 + (dbase & 7)) = pk;
}

// ---------- boundary matvec: s_out = a64*s_in + Mbf@s_in + Ufin_k
// s_in staged into LDS via L2-bypassing relaxed atomics; s_out via same.
// Mbf stays L2-resident (no fences in pass2). Rows XCD-swizzled.
__device__ __forceinline__ void mv_body(const unsigned short* __restrict__ Mbf,
                                        const float* __restrict__ sin_,
                                        const float* __restrict__ Ufin_k,
                                        float* __restrict__ sout,
                                        float* sld,
                                        float a64, int bx, int tid) {
    float tmp[8];
#pragma unroll
    for (int j = 0; j < 8; ++j)
        tmp[j] = __hip_atomic_load(sin_ + tid + j * 256, __ATOMIC_RELAXED,
                                   __HIP_MEMORY_SCOPE_AGENT);
#pragma unroll
    for (int j = 0; j < 8; ++j) sld[tid + j * 256] = tmp[j];
    __syncthreads();
    int lane = tid & 63, w = tid >> 6;
    int r0 = ((bx & 7) * 32 + (bx >> 3)) * 8 + w * 2;   // XCD x owns rows [x*256,+256)
#pragma unroll
    for (int rr = 0; rr < 2; ++rr) {
        int r = r0 + rr;
        const unsigned short* Mr = Mbf + (size_t)r * SD;
        float accu = 0.f;
#pragma unroll
        for (int it = 0; it < 4; ++it) {
            int c = lane * 8 + it * 512;
            v8s m8 = *(const v8s*)(Mr + c);
            float4 sa = *(const float4*)(sld + c);
            float4 sb = *(const float4*)(sld + c + 4);
            accu += b2f((unsigned short)m8[0]) * sa.x + b2f((unsigned short)m8[1]) * sa.y
                  + b2f((unsigned short)m8[2]) * sa.z + b2f((unsigned short)m8[3]) * sa.w
                  + b2f((unsigned short)m8[4]) * sb.x + b2f((unsigned short)m8[5]) * sb.y
                  + b2f((unsigned short)m8[6]) * sb.z + b2f((unsigned short)m8[7]) * sb.w;
        }
#pragma unroll
        for (int off = 32; off; off >>= 1) accu += __shfl_down(accu, off);
        if (lane == 0) {
            float v = a64 * sld[r] + accu + Ufin_k[r];
            __hip_atomic_store(sout + r, v, __ATOMIC_RELAXED, __HIP_MEMORY_SCOPE_AGENT);
        }
    }
}

// ---------- persistent scan kernel ----------
__global__ __launch_bounds__(256) void k_coop(const unsigned short* __restrict__ Efr,
                                              const unsigned short* __restrict__ Mbf,
                                              const float* __restrict__ s0,
                                              const float* __restrict__ pn,
                                              float* __restrict__ U32a,
                                              float* __restrict__ U32b,
                                              unsigned short* __restrict__ Ufra,
                                              unsigned short* __restrict__ Ufrb,
                                              float* __restrict__ Sb,
                                              unsigned short* __restrict__ Sfr,
                                              unsigned* flags, unsigned* genp,
                                              float a64) {
    __shared__ float sld[SD];                     // 8 KB (pass2 staging)
    int bx = blockIdx.x, tid = threadIdx.x;
    int gtid = bx * 256 + tid;
    float* U32[2] = {U32a, U32b};
    unsigned short* Ufr[2] = {Ufra, Ufrb};
    unsigned gseq = 0;

    // init pass1: u = PROC_STD * pn[k*64]
    for (int idx = gtid; idx < SD * KB; idx += 65536) {
        int kb = idx >> 11, d = idx & 2047;
        float v = PROC_STD * pn[(size_t)(kb * 64) * SD + d];
        U32a[idx] = v;
        Ufra[((size_t)(d >> 3)) * 1024 + kb * 8 + (d & 7)] = f2bf(v);
    }
    if (gtid < SD)   // Sb written ONLY via bypass atomics until pass3-init reads it
        __hip_atomic_store(Sb + gtid, s0[gtid], __ATOMIC_RELAXED,
                           __HIP_MEMORY_SCOPE_AGENT);
    gbar_f(flags, genp, bx, tid, ++gseq);

    // pass1: 63 batched noise-accumulation steps
    for (int i = 1; i <= 63; ++i) {
        step_body(Efr, Ufr[(i - 1) & 1], U32[(i - 1) & 1], U32[i & 1], Ufr[i & 1],
                  (unsigned short*)0, pn, i, 0, bx, tid);
        gbar_f(flags, genp, bx, tid, ++gseq);
    }
    // pass2: 127 sequential boundary matvecs, fence-free barriers
    for (int k = 0; k < KB - 1; ++k) {
        mv_body(Mbf, Sb + (size_t)k * SD, U32b + (size_t)k * SD,
                Sb + (size_t)(k + 1) * SD, sld, a64, bx, tid);
        gbar_nf(flags, genp, bx, tid, ++gseq);
    }
    // init pass3 from boundary states; emit S at t = kb*64
    for (int idx = gtid; idx < SD * KB; idx += 65536) {
        int kb = idx >> 11, d = idx & 2047;
        float v = __hip_atomic_load(Sb + idx, __ATOMIC_RELAXED,
                                    __HIP_MEMORY_SCOPE_AGENT);
        U32a[idx] = v;
        unsigned short bv = f2bf(v);
        Ufra[((size_t)(d >> 3)) * 1024 + kb * 8 + (d & 7)] = bv;
        Sfr[((size_t)(d >> 3)) * 65536 + (size_t)(kb * 64) * 8 + (d & 7)] = bv;
    }
    gbar_f(flags, genp, bx, tid, ++gseq);

    // pass3: 63 replay steps, streaming bf16 states into Sfr
    for (int i = 1; i <= 63; ++i) {
        step_body(Efr, Ufr[(i - 1) & 1], U32[(i - 1) & 1], U32[i & 1], Ufr[i & 1],
                  Sfr, pn, i, 1, bx, tid);
        if (i < 63) gbar_f(flags, genp, bx, tid, ++gseq);
    }
}

// ---------- final obs GEMM: out[t][o] = Cfr @ Sfr + OBS_STD * on
__global__ __launch_bounds__(256) void k_obs(const unsigned short* __restrict__ Cfr,
                                             const unsigned short* __restrict__ Sfr,
                                             const float* __restrict__ on,
                                             float* __restrict__ out) {
    int bx = blockIdx.x;
    int ot = (bx & 7) * 64, tt = (bx >> 3) * 64;
    int tid = threadIdx.x, lane = tid & 63, w = tid >> 6;
    int m16 = lane & 15, g = lane >> 4;
    int wo = (w & 1) * 32, wt = (w >> 1) * 32;
    v4f acc[2][2] = {{{0,0,0,0},{0,0,0,0}},{{0,0,0,0},{0,0,0,0}}};
    const unsigned short* Ap = Cfr + (size_t)g * 4096 + (ot + wo + m16) * 8;
    const unsigned short* Bp = Sfr + (size_t)g * 65536 + (tt + wt + m16) * 8;
#pragma unroll 4
    for (int kk = 0; kk < 64; ++kk) {
        v8s a0 = *(const v8s*)(Ap + (size_t)kk * 16384);
        v8s a1 = *(const v8s*)(Ap + (size_t)kk * 16384 + 128);
        v8s b0 = *(const v8s*)(Bp + (size_t)kk * 262144);
        v8s b1 = *(const v8s*)(Bp + (size_t)kk * 262144 + 128);
        acc[0][0] = __builtin_amdgcn_mfma_f32_16x16x32_bf16(a0, b0, acc[0][0], 0, 0, 0);
        acc[1][0] = __builtin_amdgcn_mfma_f32_16x16x32_bf16(a1, b0, acc[1][0], 0, 0, 0);
        acc[0][1] = __builtin_amdgcn_mfma_f32_16x16x32_bf16(a0, b1, acc[0][1], 0, 0, 0);
        acc[1][1] = __builtin_amdgcn_mfma_f32_16x16x32_bf16(a1, b1, acc[1][1], 0, 0, 0);
    }
#pragma unroll
    for (int mi = 0; mi < 2; ++mi)
#pragma unroll
        for (int ni = 0; ni < 2; ++ni) {
            int o = ot + wo + mi * 16 + g * 4;
            int t = tt + wt + ni * 16 + m16;
            size_t base = (size_t)t * OD + o;
            float4 n4 = *(const float4*)(on + base);
            float4 o4;
            o4.x = acc[mi][ni][0] + OBS_STD * n4.x;
            o4.y = acc[mi][ni][1] + OBS_STD * n4.y;
            o4.z = acc[mi][ni][2] + OBS_STD * n4.z;
            o4.w = acc[mi][ni][3] + OBS_STD * n4.w;
            *(float4*)(out + base) = o4;
        }
}

// ---------- host ----------
extern "C" void kernel_launch(void* const* d_in, const int* in_sizes, int n_in,
                              void* d_out, int out_size, void* d_ws, size_t ws_size,
                              hipStream_t stream) {
    const float* s0 = (const float*)d_in[0];
    const float* A  = (const float*)d_in[1];
    const float* C  = (const float*)d_in[2];
    const float* pn = (const float*)d_in[3];
    const float* on = (const float*)d_in[4];
    float* out = (float*)d_out;

    char* p = (char*)d_ws;
    auto take = [&](size_t n) { char* r = p; p += (n + 255) & ~(size_t)255; return r; };
    unsigned* bar = (unsigned*)take(65536);                              // flags + gen
    unsigned short* Efr = (unsigned short*)take((size_t)SD * SD * 2);    // 8 MB
    unsigned short* Cfr = (unsigned short*)take((size_t)OD * SD * 2);    // 2 MB
    float* U32a = (float*)take((size_t)SD * KB * 4);
    float* U32b = (float*)take((size_t)SD * KB * 4);
    unsigned short* Ufra = (unsigned short*)take((size_t)SD * KB * 2);
    unsigned short* Ufrb = (unsigned short*)take((size_t)SD * KB * 2);
    float* Sb = (float*)take((size_t)KB * SD * 4);                       // boundary states
    char* R = take((size_t)SD * NT * 2);                                 // 32 MB region
    unsigned short* Sfr  = (unsigned short*)R;            // coop/obs phase
    unsigned short* Etfr = (unsigned short*)R;            // prep phase (dead before Sfr)
    unsigned short* E3   = (unsigned short*)(R + (size_t)SD * SD * 2);
    unsigned short* E4   = (unsigned short*)(R + (size_t)SD * SD * 4);
    // d_out (16 MB) doubles as scratch until k_obs overwrites it:
    unsigned short* Mbf = (unsigned short*)d_out;                        // 8 MB
    unsigned short* E2  = (unsigned short*)((char*)d_out + (size_t)SD * SD * 2);

    // A^64 = 0.99^64 I + sum_{m=1..4} C(64,m) 0.99^(64-m) E^m
    double p99[65]; p99[0] = 1.0;
    for (int m = 1; m <= 64; ++m) p99[m] = p99[m - 1] * 0.99;
    float cf1 = (float)(64.0 * p99[63]);
    float cf2 = (float)(2016.0 * p99[62]);
    float cf3 = (float)(41664.0 * p99[61]);
    float cf4 = (float)(635376.0 * p99[60]);
    float a64 = (float)p99[64];

    hipMemsetAsync(bar, 0, 65536, stream);
    k_prep_E<<<SD * SD / 256, 256, 0, stream>>>(A, Efr, Etfr);
    k_prep_C<<<OD * SD / 256, 256, 0, stream>>>(C, Cfr);
    k_gemm_fr<<<1024, 256, 0, stream>>>(Efr, Etfr, E2);   // E^2
    k_gemm_fr<<<1024, 256, 0, stream>>>(Efr, E2, E3);     // E^3
    k_gemm_fr<<<1024, 256, 0, stream>>>(Efr, E3, E4);     // E^4
    k_combine<<<SD * SD / 256, 256, 0, stream>>>(A, E2, E3, E4, Mbf, cf1, cf2, cf3, cf4);
    k_coop<<<256, 256, 0, stream>>>(Efr, Mbf, s0, pn, U32a, U32b, Ufra, Ufrb,
                                    Sb, Sfr, bar, bar + 8192, a64);
    k_obs<<<1024, 256, 0, stream>>>(Cfr, Sfr, on, out);
}

// Round 4
// 3394.432 us; speedup vs baseline: 2.4116x; 1.0593x over previous
//
#include <hip/hip_runtime.h>

#define SD 2048      // state dim
#define OD 512       // obs dim
#define NT 8192      // steps
#define KB 128       // blocks of 64 steps
#define PROC_STD 0.31622776601683794f
#define OBS_STD  0.7071067811865476f
#define FSTRIDE 32   // flag spacing (128 B)

typedef __attribute__((ext_vector_type(8))) short v8s;
typedef __attribute__((ext_vector_type(4))) short v4s;
typedef __attribute__((ext_vector_type(4))) float v4f;

__device__ __forceinline__ unsigned short f2bf(float f) {
    union { float f; unsigned u; } v; v.f = f;
    unsigned r = v.u + 0x7fffu + ((v.u >> 16) & 1u);
    return (unsigned short)(r >> 16);
}
__device__ __forceinline__ float b2f(unsigned short u) {
    union { unsigned u; float f; } v; v.u = ((unsigned)u) << 16;
    return v.f;
}
// Relaxed agent-scope atomics: bypass L2, coherent at L3 (R3-verified cross-XCD).
__device__ __forceinline__ float aload_f(const float* p) {
    return __hip_atomic_load((float*)p, __ATOMIC_RELAXED, __HIP_MEMORY_SCOPE_AGENT);
}
__device__ __forceinline__ void astore_f(float* p, float v) {
    __hip_atomic_store(p, v, __ATOMIC_RELAXED, __HIP_MEMORY_SCOPE_AGENT);
}
__device__ __forceinline__ unsigned aload_u(const unsigned* p) {
    return __hip_atomic_load((unsigned*)p, __ATOMIC_RELAXED, __HIP_MEMORY_SCOPE_AGENT);
}
__device__ __forceinline__ void astore_u(unsigned* p, unsigned v) {
    __hip_atomic_store(p, v, __ATOMIC_RELAXED, __HIP_MEMORY_SCOPE_AGENT);
}

// ---------- frag-layout prep: element (row,col) at [(col/8)*ROWS*8 + row*8 + col%8]
__global__ __launch_bounds__(256) void k_prep_E(const float* __restrict__ A,
                                                unsigned short* __restrict__ Efr,
                                                unsigned short* __restrict__ Etfr) {
    int idx = blockIdx.x * 256 + threadIdx.x;
    int r = idx >> 11, c = idx & 2047;
    float e = A[idx] - (r == c ? 0.99f : 0.f);
    unsigned short b = f2bf(e);
    Efr [((size_t)(c >> 3)) * 16384 + r * 8 + (c & 7)] = b;  // A-layout (k=c)
    Etfr[((size_t)(r >> 3)) * 16384 + c * 8 + (r & 7)] = b;  // B-layout (k=r)
}

__global__ __launch_bounds__(256) void k_prep_C(const float* __restrict__ C,
                                                unsigned short* __restrict__ Cfr) {
    int idx = blockIdx.x * 256 + threadIdx.x;
    int o = idx >> 11, c = idx & 2047;
    Cfr[((size_t)(c >> 3)) * 4096 + o * 8 + (c & 7)] = f2bf(C[idx]);
}

// ---------- power GEMM: O = A @ B (2048^3), frag-layout, output in B-layout
__global__ __launch_bounds__(256) void k_gemm_fr(const unsigned short* __restrict__ Afr,
                                                 const unsigned short* __restrict__ Bfr,
                                                 unsigned short* __restrict__ Ofr) {
    int bx = blockIdx.x;
    int mt = (bx & 31) * 64, nt = (bx >> 5) * 64;
    int tid = threadIdx.x, lane = tid & 63, w = tid >> 6;
    int m16 = lane & 15, g = lane >> 4;
    int wm = (w & 1) * 32, wn = (w >> 1) * 32;
    v4f acc[2][2] = {{{0,0,0,0},{0,0,0,0}},{{0,0,0,0},{0,0,0,0}}};
    const unsigned short* Ap = Afr + (size_t)g * 16384 + (mt + wm + m16) * 8;
    const unsigned short* Bp = Bfr + (size_t)g * 16384 + (nt + wn + m16) * 8;
#pragma unroll 4
    for (int kk = 0; kk < 64; ++kk) {
        size_t off = (size_t)kk * 65536;
        v8s a0 = *(const v8s*)(Ap + off);
        v8s a1 = *(const v8s*)(Ap + off + 128);
        v8s b0 = *(const v8s*)(Bp + off);
        v8s b1 = *(const v8s*)(Bp + off + 128);
        acc[0][0] = __builtin_amdgcn_mfma_f32_16x16x32_bf16(a0, b0, acc[0][0], 0, 0, 0);
        acc[1][0] = __builtin_amdgcn_mfma_f32_16x16x32_bf16(a1, b0, acc[1][0], 0, 0, 0);
        acc[0][1] = __builtin_amdgcn_mfma_f32_16x16x32_bf16(a0, b1, acc[0][1], 0, 0, 0);
        acc[1][1] = __builtin_amdgcn_mfma_f32_16x16x32_bf16(a1, b1, acc[1][1], 0, 0, 0);
    }
#pragma unroll
    for (int mi = 0; mi < 2; ++mi)
#pragma unroll
        for (int ni = 0; ni < 2; ++ni) {
            int mb = mt + wm + mi * 16 + g * 4;
            int n  = nt + wn + ni * 16 + m16;
            short4 pk;
            pk.x = (short)f2bf(acc[mi][ni][0]);
            pk.y = (short)f2bf(acc[mi][ni][1]);
            pk.z = (short)f2bf(acc[mi][ni][2]);
            pk.w = (short)f2bf(acc[mi][ni][3]);
            *(short4*)(Ofr + ((size_t)(mb >> 3)) * 16384 + n * 8 + (mb & 7)) = pk;
        }
}

// ---------- Mbf = bf16( c1*E + c2*E^2 + c3*E^3 + c4*E^4 )  (A^64 = a64*I + M)
__global__ __launch_bounds__(256) void k_combine(const float* __restrict__ A,
                                                 const unsigned short* __restrict__ E2,
                                                 const unsigned short* __restrict__ E3,
                                                 const unsigned short* __restrict__ E4,
                                                 unsigned short* __restrict__ Mbf,
                                                 float c1, float c2, float c3, float c4) {
    int idx = blockIdx.x * 256 + threadIdx.x;
    int r = idx >> 11, c = idx & 2047;
    size_t fo = ((size_t)(r >> 3)) * 16384 + c * 8 + (r & 7);
    float m = c1 * (A[idx] - (r == c ? 0.99f : 0.f))
            + c2 * b2f(E2[fo]) + c3 * b2f(E3[fo]) + c4 * b2f(E4[fo]);
    Mbf[idx] = f2bf(m);
}

// ---------- fence-free grid barrier (grid=256, co-resident; relaxed atomics only)
__device__ __forceinline__ void gbar(unsigned* flags, unsigned* genp,
                                     int bx, int tid, unsigned g) {
    __syncthreads();                          // also drains this block's vmem stores
    if (bx == 0) {
        if (tid > 0) {
            while (aload_u(flags + tid * FSTRIDE) < g)
                __builtin_amdgcn_s_sleep(2);
        }
        __syncthreads();
        if (tid == 0) astore_u(genp, g);
        __syncthreads();
    } else {
        if (tid == 0) {
            astore_u(flags + bx * FSTRIDE, g);
            while (aload_u(genp) < g)
                __builtin_amdgcn_s_sleep(2);
        }
        __syncthreads();
    }
}

// ---------- one scan step: X_out = 0.99*X_in + E@X_in + PROC_STD*pn[t]  (batch 128)
// Tile 64 rows x 16 cols. E: normal loads (L2-resident, 1 MB/XCD band).
// X: atomics only. B-slice staged once/block into LDS (XOR-swizzled).
__device__ __forceinline__ void step_body(const unsigned short* __restrict__ Efr,
                                          const unsigned* __restrict__ UfrIn_u,
                                          const float* __restrict__ X32in,
                                          float* __restrict__ X32out,
                                          unsigned* __restrict__ UfrOut_u,
                                          unsigned short* __restrict__ Sfr,
                                          const float* __restrict__ pn,
                                          unsigned* ldsu,
                                          int i, int pass3, int bx, int tid) {
    int lane = tid & 63, w = tid >> 6;
    int m16 = lane & 15, g = lane >> 4;
    int mt = (bx & 7) * 4 + ((bx >> 3) & 3);  // XCD band: rows [xcd*256, +256)
    int nt = bx >> 5;                         // 8 col-groups of 16
    // stage B slice (cols nt*16..+16, all k) into LDS: 16K uints = 64 KB
#pragma unroll 16
    for (int s = 0; s < 64; ++s) {
        int g8 = s * 4 + w;
        unsigned u = aload_u(UfrIn_u + g8 * 512 + nt * 64 + lane);
        ldsu[g8 * 64 + (lane ^ ((g8 & 7) << 2))] = u;
    }
    int kb = nt * 16 + m16;
    int dbase = mt * 64 + w * 16 + g * 4;
    size_t i32 = (size_t)kb * SD + dbase;
    float xin0 = aload_f(X32in + i32);
    float xin1 = aload_f(X32in + i32 + 1);
    float xin2 = aload_f(X32in + i32 + 2);
    float xin3 = aload_f(X32in + i32 + 3);
    float4 pn4 = *(const float4*)(pn + (size_t)(kb * 64 + i - pass3) * SD + dbase);
    __syncthreads();
    int drow = mt * 64 + w * 16 + m16;
    const unsigned short* Ap = Efr + (size_t)g * 16384 + drow * 8;
    v4f acc = {0, 0, 0, 0};
#pragma unroll 8
    for (int kk = 0; kk < 64; ++kk) {
        v8s a = *(const v8s*)(Ap + (size_t)kk * 65536);
        int g8 = kk * 4 + g;
        v8s b = *(const v8s*)(ldsu + g8 * 64 + ((m16 * 4) ^ ((g8 & 7) << 2)));
        acc = __builtin_amdgcn_mfma_f32_16x16x32_bf16(a, b, acc, 0, 0, 0);
    }
    float vo0 = 0.99f * xin0 + acc[0] + PROC_STD * pn4.x;
    float vo1 = 0.99f * xin1 + acc[1] + PROC_STD * pn4.y;
    float vo2 = 0.99f * xin2 + acc[2] + PROC_STD * pn4.z;
    float vo3 = 0.99f * xin3 + acc[3] + PROC_STD * pn4.w;
    astore_f(X32out + i32,     vo0);
    astore_f(X32out + i32 + 1, vo1);
    astore_f(X32out + i32 + 2, vo2);
    astore_f(X32out + i32 + 3, vo3);
    unsigned u0 = (unsigned)f2bf(vo0) | ((unsigned)f2bf(vo1) << 16);
    unsigned u1 = (unsigned)f2bf(vo2) | ((unsigned)f2bf(vo3) << 16);
    int g8o = dbase >> 3, hh = (g & 1) * 2;
    astore_u(UfrOut_u + g8o * 512 + kb * 4 + hh,     u0);
    astore_u(UfrOut_u + g8o * 512 + kb * 4 + hh + 1, u1);
    if (pass3) {   // normal stores; consumed by k_obs after kernel-end flush
        unsigned short* sp = Sfr + (size_t)g8o * 65536 + (size_t)(kb * 64 + i) * 8
                           + (dbase & 7);
        *(unsigned*)(sp)     = u0;
        *(unsigned*)(sp + 2) = u1;
    }
}

// ---------- boundary matvec: s_out = a64*s_in + Mbf@s_in + Ufin_k
// Mbf normal loads (L2-resident band); s via bypass atomics; LDS conflict-free.
__device__ __forceinline__ void mv_body(const unsigned short* __restrict__ Mbf,
                                        const float* __restrict__ sin_,
                                        const float* __restrict__ Ufin_k,
                                        float* __restrict__ sout,
                                        float* sld, float a64, int bx, int tid) {
    float tmp[8];
#pragma unroll
    for (int j = 0; j < 8; ++j) tmp[j] = aload_f(sin_ + tid + j * 256);
#pragma unroll
    for (int j = 0; j < 8; ++j) sld[tid + j * 256] = tmp[j];
    __syncthreads();
    int lane = tid & 63, w = tid >> 6;
    int r0 = ((bx & 7) * 32 + (bx >> 3)) * 8 + w * 2;   // XCD x owns rows [x*256,+256)
#pragma unroll
    for (int rr = 0; rr < 2; ++rr) {
        int r = r0 + rr;
        const unsigned short* Mr = Mbf + (size_t)r * SD;
        float accu = 0.f;
#pragma unroll
        for (int it = 0; it < 8; ++it) {
            int c = it * 256 + lane * 4;                // contiguous: bank-conflict-free
            v4s m4 = *(const v4s*)(Mr + c);
            float4 s4 = *(const float4*)(sld + c);
            accu += b2f((unsigned short)m4[0]) * s4.x + b2f((unsigned short)m4[1]) * s4.y
                  + b2f((unsigned short)m4[2]) * s4.z + b2f((unsigned short)m4[3]) * s4.w;
        }
#pragma unroll
        for (int off = 32; off; off >>= 1) accu += __shfl_down(accu, off);
        if (lane == 0) {
            float v = a64 * sld[r] + accu + aload_f(Ufin_k + r);
            astore_f(sout + r, v);
        }
    }
}

// ---------- persistent scan kernel: NO fences anywhere ----------
__global__ __launch_bounds__(256) void k_coop(const unsigned short* __restrict__ Efr,
                                              const unsigned short* __restrict__ Mbf,
                                              const float* __restrict__ s0,
                                              const float* __restrict__ pn,
                                              float* __restrict__ U32a,
                                              float* __restrict__ U32b,
                                              unsigned* __restrict__ Ufra_u,
                                              unsigned* __restrict__ Ufrb_u,
                                              float* __restrict__ Sb,
                                              unsigned short* __restrict__ Sfr,
                                              unsigned* flags, unsigned* genp,
                                              float a64) {
    __shared__ unsigned ldsu[16384];              // 64 KB
    int bx = blockIdx.x, tid = threadIdx.x;
    int gtid = bx * 256 + tid;
    float* U32[2] = {U32a, U32b};
    unsigned* Ufr[2] = {Ufra_u, Ufrb_u};
    unsigned gseq = 0;

    // init pass1: u = PROC_STD * pn[k*64]; all mutable writes via atomics
    for (int idx = gtid; idx < SD * KB / 2; idx += 65536) {
        int kb = idx >> 10, d = (idx & 1023) * 2;
        const float* pp = pn + (size_t)(kb * 64) * SD + d;
        float v0 = PROC_STD * pp[0], v1 = PROC_STD * pp[1];
        astore_f(U32a + (size_t)kb * SD + d,     v0);
        astore_f(U32a + (size_t)kb * SD + d + 1, v1);
        astore_u(Ufra_u + (d >> 3) * 512 + kb * 4 + ((d & 7) >> 1),
                 (unsigned)f2bf(v0) | ((unsigned)f2bf(v1) << 16));
    }
    if (gtid < SD) astore_f(Sb + gtid, s0[gtid]);
    gbar(flags, genp, bx, tid, ++gseq);

    // pass1: 63 batched noise-accumulation steps
    for (int i = 1; i <= 63; ++i) {
        step_body(Efr, Ufr[(i - 1) & 1], U32[(i - 1) & 1], U32[i & 1], Ufr[i & 1],
                  (unsigned short*)0, pn, ldsu, i, 0, bx, tid);
        gbar(flags, genp, bx, tid, ++gseq);
    }
    // pass2: 127 sequential boundary matvecs
    for (int k = 0; k < KB - 1; ++k) {
        mv_body(Mbf, Sb + (size_t)k * SD, U32b + (size_t)k * SD,
                Sb + (size_t)(k + 1) * SD, (float*)ldsu, a64, bx, tid);
        gbar(flags, genp, bx, tid, ++gseq);
    }
    // init pass3 from boundary states; emit S at t = kb*64 (normal stores to Sfr)
    for (int idx = gtid; idx < SD * KB / 2; idx += 65536) {
        int kb = idx >> 10, d = (idx & 1023) * 2;
        float v0 = aload_f(Sb + (size_t)kb * SD + d);
        float v1 = aload_f(Sb + (size_t)kb * SD + d + 1);
        astore_f(U32a + (size_t)kb * SD + d,     v0);
        astore_f(U32a + (size_t)kb * SD + d + 1, v1);
        unsigned u = (unsigned)f2bf(v0) | ((unsigned)f2bf(v1) << 16);
        astore_u(Ufra_u + (d >> 3) * 512 + kb * 4 + ((d & 7) >> 1), u);
        *(unsigned*)(Sfr + (size_t)(d >> 3) * 65536 + (size_t)(kb * 64) * 8 + (d & 7)) = u;
    }
    gbar(flags, genp, bx, tid, ++gseq);

    // pass3: 63 replay steps, streaming bf16 states into Sfr
    for (int i = 1; i <= 63; ++i) {
        step_body(Efr, Ufr[(i - 1) & 1], U32[(i - 1) & 1], U32[i & 1], Ufr[i & 1],
                  Sfr, pn, ldsu, i, 1, bx, tid);
        if (i < 63) gbar(flags, genp, bx, tid, ++gseq);
    }
}

// ---------- final obs GEMM: out[t][o] = Cfr @ Sfr + OBS_STD * on
__global__ __launch_bounds__(256) void k_obs(const unsigned short* __restrict__ Cfr,
                                             const unsigned short* __restrict__ Sfr,
                                             const float* __restrict__ on,
                                             float* __restrict__ out) {
    int bx = blockIdx.x;
    int ot = (bx & 7) * 64, tt = (bx >> 3) * 64;
    int tid = threadIdx.x, lane = tid & 63, w = tid >> 6;
    int m16 = lane & 15, g = lane >> 4;
    int wo = (w & 1) * 32, wt = (w >> 1) * 32;
    v4f acc[2][2] = {{{0,0,0,0},{0,0,0,0}},{{0,0,0,0},{0,0,0,0}}};
    const unsigned short* Ap = Cfr + (size_t)g * 4096 + (ot + wo + m16) * 8;
    const unsigned short* Bp = Sfr + (size_t)g * 65536 + (tt + wt + m16) * 8;
#pragma unroll 4
    for (int kk = 0; kk < 64; ++kk) {
        v8s a0 = *(const v8s*)(Ap + (size_t)kk * 16384);
        v8s a1 = *(const v8s*)(Ap + (size_t)kk * 16384 + 128);
        v8s b0 = *(const v8s*)(Bp + (size_t)kk * 262144);
        v8s b1 = *(const v8s*)(Bp + (size_t)kk * 262144 + 128);
        acc[0][0] = __builtin_amdgcn_mfma_f32_16x16x32_bf16(a0, b0, acc[0][0], 0, 0, 0);
        acc[1][0] = __builtin_amdgcn_mfma_f32_16x16x32_bf16(a1, b0, acc[1][0], 0, 0, 0);
        acc[0][1] = __builtin_amdgcn_mfma_f32_16x16x32_bf16(a0, b1, acc[0][1], 0, 0, 0);
        acc[1][1] = __builtin_amdgcn_mfma_f32_16x16x32_bf16(a1, b1, acc[1][1], 0, 0, 0);
    }
#pragma unroll
    for (int mi = 0; mi < 2; ++mi)
#pragma unroll
        for (int ni = 0; ni < 2; ++ni) {
            int o = ot + wo + mi * 16 + g * 4;
            int t = tt + wt + ni * 16 + m16;
            size_t base = (size_t)t * OD + o;
            float4 n4 = *(const float4*)(on + base);
            float4 o4;
            o4.x = acc[mi][ni][0] + OBS_STD * n4.x;
            o4.y = acc[mi][ni][1] + OBS_STD * n4.y;
            o4.z = acc[mi][ni][2] + OBS_STD * n4.z;
            o4.w = acc[mi][ni][3] + OBS_STD * n4.w;
            *(float4*)(out + base) = o4;
        }
}

// ---------- host ----------
extern "C" void kernel_launch(void* const* d_in, const int* in_sizes, int n_in,
                              void* d_out, int out_size, void* d_ws, size_t ws_size,
                              hipStream_t stream) {
    const float* s0 = (const float*)d_in[0];
    const float* A  = (const float*)d_in[1];
    const float* C  = (const float*)d_in[2];
    const float* pn = (const float*)d_in[3];
    const float* on = (const float*)d_in[4];
    float* out = (float*)d_out;

    char* p = (char*)d_ws;
    auto take = [&](size_t n) { char* r = p; p += (n + 255) & ~(size_t)255; return r; };
    unsigned* bar = (unsigned*)take(65536);                              // flags + gen
    unsigned short* Efr = (unsigned short*)take((size_t)SD * SD * 2);    // 8 MB
    unsigned short* Cfr = (unsigned short*)take((size_t)OD * SD * 2);    // 2 MB
    float* U32a = (float*)take((size_t)SD * KB * 4);
    float* U32b = (float*)take((size_t)SD * KB * 4);
    unsigned* Ufra = (unsigned*)take((size_t)SD * KB * 2);
    unsigned* Ufrb = (unsigned*)take((size_t)SD * KB * 2);
    float* Sb = (float*)take((size_t)KB * SD * 4);                       // boundary states
    char* R = take((size_t)SD * NT * 2);                                 // 32 MB region
    unsigned short* Sfr  = (unsigned short*)R;            // coop/obs phase
    unsigned short* Etfr = (unsigned short*)R;            // prep phase (dead before Sfr)
    unsigned short* E3   = (unsigned short*)(R + (size_t)SD * SD * 2);
    unsigned short* E4   = (unsigned short*)(R + (size_t)SD * SD * 4);
    // d_out (16 MB) doubles as scratch until k_obs overwrites it:
    unsigned short* Mbf = (unsigned short*)d_out;                        // 8 MB
    unsigned short* E2  = (unsigned short*)((char*)d_out + (size_t)SD * SD * 2);

    // A^64 = 0.99^64 I + sum_{m=1..4} C(64,m) 0.99^(64-m) E^m
    double p99[65]; p99[0] = 1.0;
    for (int m = 1; m <= 64; ++m) p99[m] = p99[m - 1] * 0.99;
    float cf1 = (float)(64.0 * p99[63]);
    float cf2 = (float)(2016.0 * p99[62]);
    float cf3 = (float)(41664.0 * p99[61]);
    float cf4 = (float)(635376.0 * p99[60]);
    float a64 = (float)p99[64];

    hipMemsetAsync(bar, 0, 65536, stream);
    k_prep_E<<<SD * SD / 256, 256, 0, stream>>>(A, Efr, Etfr);
    k_prep_C<<<OD * SD / 256, 256, 0, stream>>>(C, Cfr);
    k_gemm_fr<<<1024, 256, 0, stream>>>(Efr, Etfr, E2);   // E^2
    k_gemm_fr<<<1024, 256, 0, stream>>>(Efr, E2, E3);     // E^3
    k_gemm_fr<<<1024, 256, 0, stream>>>(Efr, E3, E4);     // E^4
    k_combine<<<SD * SD / 256, 256, 0, stream>>>(A, E2, E3, E4, Mbf, cf1, cf2, cf3, cf4);
    k_coop<<<256, 256, 0, stream>>>(Efr, Mbf, s0, pn, U32a, U32b, Ufra, Ufrb,
                                    Sb, Sfr, bar, bar + 8192, a64);
    k_obs<<<1024, 256, 0, stream>>>(Cfr, Sfr, on, out);
}